// Round 12
// baseline (50.579 us; speedup 1.0000x reference)
//
#include <hip/hip_runtime.h>
#include <hip/hip_bf16.h>

// MyDeConv1D as GEMM: out[b,t,f] = sum_{j,c} x[b,t+28-4j,c]*W[c,j,f] + cnt(t)*256*bias[f]
// M=32768, N=256, K=2048, bf16 MFMA 16x16x32.
// R12: global_load_lds (unsinkable) + counted vmcnt + raw s_barrier pipeline.
//   Block 128r x 128f, 256 thr, 4 waves (64x64 each), 512 blocks = 2/CU.
//   64 phases of K=32. x staged f32 via gload_lds -> per-chunk LDS bf16
//   conversion pass (hidden in phases 6/7). Wf pre-swizzled to LDS image.
//   B triple-buffered, stage-2-ahead. LDS 63 KB static.

#define B_   16
#define T_   2048
#define C_   256
#define KT   8
#define F_   256
#define SH   28
#define BT   128
#define WIN  (BT + SH)           // 156 window rows
#define AF32_OFF 0               // float[156*32]  = 19968 B
#define ABF_OFF  19968           // 2 x ushort[156*32] = 2*9984 B
#define BB_OFF   39936           // 3 x 8192 B
// total 64512 B

typedef __attribute__((ext_vector_type(8))) short short8;
typedef __attribute__((ext_vector_type(4))) float floatx4;

__device__ inline void gload16(const void* g, void* l) {
    __builtin_amdgcn_global_load_lds(
        (const __attribute__((address_space(1))) void*)g,
        (__attribute__((address_space(3))) void*)l, 16, 0, 0);
}

__device__ inline short8 cvt8(float4 a, float4 b) {
    float v[8] = {a.x, a.y, a.z, a.w, b.x, b.y, b.z, b.w};
    short8 r;
    #pragma unroll
    for (int i = 0; i < 8; ++i) {
        __hip_bfloat16 h = __float2bfloat16(v[i]);
        r[i] = *reinterpret_cast<const short*>(&h);
    }
    return r;
}

// Wf = exact LDS image per tile (S = c*8 + j, fh): [128 f][4 granules],
// phys granule p = q ^ ((f>>1)&3); granule (f,q) holds c = c*32 + q*8 + i.
__global__ __launch_bounds__(256) void wprep_kernel(const float* __restrict__ W,
                                                    ushort* __restrict__ Wf) {
    const int o  = blockIdx.x * 256 + threadIdx.x;   // granule id 0..65535
    const int gg = o & 511;
    const int tf = o >> 9;
    const int fh = tf & 1;
    const int S  = tf >> 1;                          // 0..63
    const int j  = S & 7, c = S >> 3;
    const int fl = gg >> 2, p = gg & 3;
    const int q  = p ^ ((fl >> 1) & 3);
    const int f  = fh * 128 + fl;
    const int c0 = c * 32 + q * 8;
    short8 pk;
    #pragma unroll
    for (int i = 0; i < 8; ++i) {
        __hip_bfloat16 h = __float2bfloat16(W[((c0 + i) * KT + j) * F_ + f]);
        pk[i] = *reinterpret_cast<const short*>(&h);
    }
    *reinterpret_cast<short8*>(Wf + (size_t)o * 8) = pk;
}

__global__ __launch_bounds__(256, 2) void deconv_kernel(
        const float* __restrict__ x, const ushort* __restrict__ Wf,
        const float* __restrict__ bias, float* __restrict__ out) {
    __shared__ alignas(16) char smem[64512];
    const int bid = blockIdx.x;                 // (tt*16 + b)*2 + fh
    const int fh  = bid & 1;
    const int tb  = bid >> 1;
    const int b   = tb & 15;
    const int t0  = (tb >> 4) * BT;
    const int tid = threadIdx.x;
    const int w   = tid >> 6, lane = tid & 63;
    const int l16 = lane & 15, q = lane >> 4;
    const int wm  = w >> 1, wf2 = w & 1;
    const int rA  = wm * 64 + l16;              // A row base (+ SH-4j + mf*16)
    const int flb = wf2 * 64 + l16;             // B f_local base (+ nf*16)

    float*  Af = (float*)(smem + AF32_OFF);
    ushort* Ab = (ushort*)(smem + ABF_OFF);     // + p2*4992 (ushorts)
    ushort* Bb = (ushort*)(smem + BB_OFF);      // + buf*4096 (ushorts)

#define VMW(N_) do { asm volatile("s_waitcnt vmcnt(" #N_ ")" ::: "memory"); \
        __builtin_amdgcn_sched_barrier(0); } while (0)
#define LKW() do { asm volatile("s_waitcnt lgkmcnt(0)" ::: "memory");       \
        __builtin_amdgcn_sched_barrier(0); } while (0)
#define BAR() do { __builtin_amdgcn_sched_barrier(0);                       \
        __builtin_amdgcn_s_barrier();                                       \
        asm volatile("" ::: "memory");                                      \
        __builtin_amdgcn_sched_barrier(0); } while (0)

    // stage one A round (k=0..4) of chunk cc: f32 granules u = k*256+tid,
    // row = u>>3 (128B rows), g = u&7. Linear LDS fill, src row clamped.
#define A_ROUND(k_, cc_) do {                                               \
        const int u_ = (k_) * 256 + tid;                                    \
        if ((k_) < 4 || u_ < WIN * 8) {                                     \
            const int row_ = u_ >> 3, g_ = u_ & 7;                          \
            int tr_ = t0 + row_; if (tr_ > T_ - 1) tr_ = T_ - 1;            \
            const float* src_ = x + ((size_t)(b * T_ + tr_) * C_ +          \
                                     (cc_) * 32 + g_ * 4);                  \
            gload16(src_, smem + AF32_OFF + ((k_) * 256 + w * 64) * 16);    \
        } } while (0)

    // stage B tile S (2 gload rounds of 256 thr x 16B), linear copy
#define B_STAGE(S_) do {                                                    \
        const ushort* s0_ = Wf + (((size_t)(S_) * 2 + fh) * 4096);          \
        char* l0_ = smem + BB_OFF + ((S_) % 3) * 8192;                      \
        gload16(s0_ + tid * 8,         l0_ + (w * 64) * 16);                \
        gload16(s0_ + 2048 + tid * 8,  l0_ + (256 + w * 64) * 16);          \
        } while (0)

    // LDS f32 -> bf16 tile conversion, one round (r=0..2), dest parity p2
#define CVT_ROUND(r_, p2_) do {                                             \
        const int task_ = (r_) * 256 + tid;                                 \
        if ((r_) < 2 || task_ < WIN * 4) {                                  \
            const int row_ = task_ >> 2, qq_ = task_ & 3;                   \
            const int pp_ = (qq_ + row_) & 3;                               \
            short8 pk_ = {0, 0, 0, 0, 0, 0, 0, 0};                          \
            if (t0 + row_ < T_) {                                           \
                const float* fp_ = Af + row_ * 32 + pp_ * 8;                \
                float4 u0_ = *(const float4*)fp_;                           \
                float4 u1_ = *(const float4*)(fp_ + 4);                     \
                pk_ = cvt8(u0_, u1_);                                       \
            }                                                               \
            *(short8*)(Ab + (p2_) * 4992 + row_ * 32 +                      \
                       ((pp_ ^ ((row_ >> 1) & 3)) * 8)) = pk_;              \
        } } while (0)

#define MFMA_PHASE(c_, jj_) do {                                            \
        const ushort* ab_ = Ab + ((c_) & 1) * 4992;                         \
        const ushort* bb_ = Bb + ((((c_) * 8 + (jj_)) % 3)) * 4096;         \
        short8 afr_[4], bfr_[4];                                            \
        _Pragma("unroll")                                                   \
        for (int mf = 0; mf < 4; ++mf) {                                    \
            const int row_ = rA + (SH - 4 * (jj_)) + mf * 16;               \
            afr_[mf] = *(const short8*)(ab_ + row_ * 32 +                   \
                        ((q ^ ((row_ >> 1) & 3)) * 8));                     \
        }                                                                   \
        _Pragma("unroll")                                                   \
        for (int nf = 0; nf < 4; ++nf) {                                    \
            const int fl_ = flb + nf * 16;                                  \
            bfr_[nf] = *(const short8*)(bb_ + fl_ * 32 +                    \
                        ((q ^ ((fl_ >> 1) & 3)) * 8));                      \
        }                                                                   \
        __builtin_amdgcn_s_setprio(1);                                      \
        _Pragma("unroll")                                                   \
        for (int mf = 0; mf < 4; ++mf)                                      \
            _Pragma("unroll")                                               \
            for (int nf = 0; nf < 4; ++nf)                                  \
                acc[mf][nf] = __builtin_amdgcn_mfma_f32_16x16x32_bf16(      \
                    afr_[mf], bfr_[nf], acc[mf][nf], 0, 0, 0);              \
        __builtin_amdgcn_s_setprio(0);                                      \
        } while (0)

#define PHASE(jj_, NN_, DOA_, CV_) do {                                     \
        if (DOA_) A_ROUND(jj_, c + 1);                                      \
        B_STAGE(c * 8 + (jj_) + 2);                                         \
        VMW(NN_);                                                           \
        BAR();                                                              \
        MFMA_PHASE(c, jj_);                                                 \
        if ((CV_) == 1) { CVT_ROUND(0, (c + 1) & 1);                        \
                          CVT_ROUND(1, (c + 1) & 1); LKW(); }               \
        if ((CV_) == 2) { CVT_ROUND(2, (c + 1) & 1); LKW(); }               \
        BAR();                                                              \
        } while (0)

#define PHASE7(jj_, NN_, DOB_) do {                                         \
        if (DOB_) B_STAGE(56 + (jj_) + 2);                                  \
        VMW(NN_);                                                           \
        BAR();                                                              \
        MFMA_PHASE(7, jj_);                                                 \
        BAR();                                                              \
        } while (0)

    float bf4[4];
    #pragma unroll
    for (int nf = 0; nf < 4; ++nf) bf4[nf] = bias[fh * 128 + flb + nf * 16];

    floatx4 acc[4][4];
    #pragma unroll
    for (int mf = 0; mf < 4; ++mf)
        #pragma unroll
        for (int nf = 0; nf < 4; ++nf)
            acc[mf][nf] = (floatx4){0.f, 0.f, 0.f, 0.f};

    // ---- prologue: stage chunk 0 (f32) + B[0],B[1]; convert chunk 0 ----
    A_ROUND(0, 0); A_ROUND(1, 0); A_ROUND(2, 0); A_ROUND(3, 0); A_ROUND(4, 0);
    B_STAGE(0); B_STAGE(1);
    VMW(4);                       // retire all A rounds, keep B[0],B[1] (2x2 ops)
    BAR();
    CVT_ROUND(0, 0); CVT_ROUND(1, 0); CVT_ROUND(2, 0);
    LKW();
    BAR();

    for (int c = 0; c < 7; ++c) {
        PHASE(0, 5, 1, 0);
        PHASE(1, 6, 1, 0);
        PHASE(2, 6, 1, 0);
        PHASE(3, 6, 1, 0);
        PHASE(4, 6, 1, 0);
        PHASE(5, 5, 0, 0);
        PHASE(6, 4, 0, 1);
        PHASE(7, 4, 0, 2);
    }
    // last chunk: no A staging, B stages only while S+2 <= 63
    PHASE7(0, 4, 1); PHASE7(1, 4, 1); PHASE7(2, 4, 1); PHASE7(3, 4, 1);
    PHASE7(4, 4, 1); PHASE7(5, 4, 1); PHASE7(6, 2, 0); PHASE7(7, 0, 0);

    // ---- epilogue: + cnt(t)*256*bias; C/D map col=l16 (f), row=q*4+r ----
    #pragma unroll
    for (int mf = 0; mf < 4; ++mf) {
        #pragma unroll
        for (int nf = 0; nf < 4; ++nf) {
            const int f = fh * 128 + flb + nf * 16;
            #pragma unroll
            for (int r = 0; r < 4; ++r) {
                const int t = t0 + wm * 64 + mf * 16 + q * 4 + r;
                const int jmin = (t < T_ - SH) ? 0 : (((t - (T_ - SH)) >> 2) + 1);
                out[(size_t)(b * T_ + t) * F_ + f] =
                    acc[mf][nf][r] + (float)(8 - jmin) * 256.0f * bf4[nf];
            }
        }
    }
#undef VMW
#undef LKW
#undef BAR
#undef A_ROUND
#undef B_STAGE
#undef CVT_ROUND
#undef MFMA_PHASE
#undef PHASE
#undef PHASE7
}

extern "C" void kernel_launch(void* const* d_in, const int* in_sizes, int n_in,
                              void* d_out, int out_size, void* d_ws, size_t ws_size,
                              hipStream_t stream) {
    const float* x    = (const float*)d_in[0];
    const float* W    = (const float*)d_in[1];   // (C,KT,F)
    const float* bias = (const float*)d_in[2];
    float* out = (float*)d_out;
    ushort* Wf = (ushort*)d_ws;                  // 1 MiB scratch

    wprep_kernel<<<256, 256, 0, stream>>>(W, Wf);
    deconv_kernel<<<512, 256, 0, stream>>>(x, Wf, bias, out);
}

// Round 14
// 44.241 us; speedup vs baseline: 1.1432x; 1.1432x over previous
//
#include <hip/hip_runtime.h>
#include <hip/hip_bf16.h>

// MyDeConv1D as GEMM: out[b,t,f] = sum_{j,c} x[b,t+28-4j,c]*W[c,j,f] + cnt(t)*256*bias[f]
// M=32768, N=256, K=2048, bf16 MFMA 16x16x32.
// R14 = R13 with the asm B-load fixed to the flat 64-bit-vaddr form.
//   Fat phases (128 MFMA/wave between barriers) + pinned asm B-loads +
//   counted vmcnt + global_load_lds A-staging with source-permuted granules.
//   Block 128r x 128f, 4 waves (2m x 2f), 512 blocks = 2/CU. 8 chunks of 32ch,
//   2 barriers/chunk. All LDS patterns bank-walked to the b128 floor.

#define B_   16
#define T_   2048
#define C_   256
#define KT   8
#define F_   256
#define SH   28
#define BT   128
#define WIN  (BT + SH)          // 156 rows
#define FB   19968              // bytes per f32 chunk buffer (156*8 granules)
#define ABFB 9984               // bytes per bf16 tile buffer (156*4 granules)
#define ABF  (2 * FB)           // bf16 tiles base offset (39936)
// total LDS = 2*FB + 2*ABFB = 59904 B

typedef __attribute__((ext_vector_type(8))) short short8;
typedef __attribute__((ext_vector_type(4))) float floatx4;
typedef __attribute__((ext_vector_type(4))) int   intx4;

__device__ inline void gload16(const void* g, void* l) {
    __builtin_amdgcn_global_load_lds(
        (const __attribute__((address_space(1))) void*)g,
        (__attribute__((address_space(3))) void*)l, 16, 0, 0);
}

__device__ inline short8 cvt8(float4 a, float4 b) {
    float v[8] = {a.x, a.y, a.z, a.w, b.x, b.y, b.z, b.w};
    short8 r;
    #pragma unroll
    for (int i = 0; i < 8; ++i) {
        __hip_bfloat16 h = __float2bfloat16(v[i]);
        r[i] = *reinterpret_cast<const short*>(&h);
    }
    return r;
}

// Wf frag order: fid = S*16 + g, S = c*8 + j. frag (S,g): lane(l16,q) holds
// B[k=q*8+i][f=g*16+l16], c = c*32 + q*8 + i. 1KB/frag coalesced.
__global__ __launch_bounds__(256) void wprep_kernel(const float* __restrict__ W,
                                                    ushort* __restrict__ Wf) {
    const int tid  = threadIdx.x;
    const int fid  = blockIdx.x * 4 + (tid >> 6);   // 0..1023
    const int lane = tid & 63;
    const int g    = fid & 15;
    const int S    = fid >> 4;
    const int j    = S & 7, c = S >> 3;
    const int c0   = c * 32 + (lane >> 4) * 8;
    const int f    = g * 16 + (lane & 15);
    short8 pk;
    #pragma unroll
    for (int i = 0; i < 8; ++i) {
        __hip_bfloat16 h = __float2bfloat16(W[((c0 + i) * KT + j) * F_ + f]);
        pk[i] = *reinterpret_cast<const short*>(&h);
    }
    *reinterpret_cast<short8*>(Wf + (size_t)fid * 512 + lane * 8) = pk;
}

__global__ __launch_bounds__(256, 2) void deconv_kernel(
        const float* __restrict__ x, const ushort* __restrict__ Wf,
        const float* __restrict__ bias, float* __restrict__ out) {
    __shared__ alignas(16) char smem[59904];
    const int bid = blockIdx.x;                 // (tt*16 + b)*2 + fh
    const int fh  = bid & 1;
    const int tb  = bid >> 1;
    const int b   = tb & 15;
    const int t0  = (tb >> 4) * BT;
    const int tid = threadIdx.x;
    const int w   = tid >> 6, lane = tid & 63;
    const int l16 = lane & 15, q = lane >> 4;
    const int wm  = w >> 1, wf2 = w & 1;
    // per-lane B base: frag g0 = fh*8 + wf2*4 (+nf), lane stride 16B
    const char* wfbase = (const char*)Wf +
        (size_t)(fh * 8 + wf2 * 4) * 1024 + (size_t)lane * 16;

#define VMW(N_) do { asm volatile("s_waitcnt vmcnt(" #N_ ")" ::: "memory"); \
        __builtin_amdgcn_sched_barrier(0); } while (0)
#define LKW() do { asm volatile("s_waitcnt lgkmcnt(0)" ::: "memory");       \
        __builtin_amdgcn_sched_barrier(0); } while (0)
#define BAR() do { __builtin_amdgcn_sched_barrier(0);                       \
        __builtin_amdgcn_s_barrier();                                       \
        asm volatile("" ::: "memory");                                      \
        __builtin_amdgcn_sched_barrier(0); } while (0)

    // A stage round k for chunk cc -> Fbuf[cc&1]. Linear dest (granule u);
    // source granule v = (s - row) mod 8 pre-permuted so CVT reads are uniform.
#define A_ROUND(k_, cc_) do {                                               \
        const int u_ = (k_) * 256 + tid;                                    \
        if ((k_) < 4 || tid < 224) {                                        \
            const int row_ = u_ >> 3, s_ = u_ & 7;                          \
            const int v_   = (s_ + 8 - (row_ & 7)) & 7;                     \
            int tr_ = t0 + row_; if (tr_ > T_ - 1) tr_ = T_ - 1;            \
            gload16(x + ((size_t)(b * T_ + tr_) * C_ + (cc_) * 32 + v_ * 4),\
                    smem + ((cc_) & 1) * FB + ((k_) * 256 + w * 64) * 16);  \
        } } while (0)

    // pinned B frag loads (flat 64b vaddr form), tile S -> ring slot sl
#define B_ISSUE(S_, sl_) do {                                               \
        const char* p_ = wfbase + (size_t)(S_) * 16384;                     \
        asm volatile("global_load_dwordx4 %0, %1, off"                      \
            : "=v"(bR[sl_][0]) : "v"(p_) : "memory");                       \
        asm volatile("global_load_dwordx4 %0, %1, off offset:1024"          \
            : "=v"(bR[sl_][1]) : "v"(p_) : "memory");                       \
        asm volatile("global_load_dwordx4 %0, %1, off offset:2048"          \
            : "=v"(bR[sl_][2]) : "v"(p_) : "memory");                       \
        asm volatile("global_load_dwordx4 %0, %1, off offset:3072"          \
            : "=v"(bR[sl_][3]) : "v"(p_) : "memory");                       \
        } while (0)

    // f32 -> bf16 convert round r for chunk parity par (reads Fbuf, writes Abuf)
#define CVT_ROUND(r_, par_) do {                                            \
        if ((r_) < 2 || tid < 112) {                                        \
            const int task_ = (r_) * 256 + tid;                             \
            const int row_ = task_ >> 2, g_ = task_ & 3;                    \
            const int s1_ = (2 * g_ + row_) & 7;                            \
            const int s2_ = (2 * g_ + 1 + row_) & 7;                        \
            const char* fb_ = smem + (par_) * FB;                           \
            float4 u0_ = *(const float4*)(fb_ + (row_ * 8 + s1_) * 16);     \
            float4 u1_ = *(const float4*)(fb_ + (row_ * 8 + s2_) * 16);     \
            short8 pk_ = {0,0,0,0,0,0,0,0};                                 \
            if (t0 + row_ < T_) pk_ = cvt8(u0_, u1_);                       \
            const int p_ = g_ ^ ((row_ >> 1) & 3);                          \
            *(short8*)(smem + ABF + (par_) * ABFB + (row_ * 4 + p_) * 16)   \
                = pk_;                                                      \
        } } while (0)

#define MFMA_TAP(c_, j_) do {                                               \
        const char* ab_ = smem + ABF + ((c_) & 1) * ABFB;                   \
        short8 af_[4];                                                      \
        _Pragma("unroll")                                                   \
        for (int mf = 0; mf < 4; ++mf) {                                    \
            const int row_ = wm * 64 + (SH - 4 * (j_)) + mf * 16 + l16;     \
            const int p_   = q ^ ((row_ >> 1) & 3);                         \
            af_[mf] = *(const short8*)(ab_ + (row_ * 4 + p_) * 16);         \
        }                                                                   \
        __builtin_amdgcn_s_setprio(1);                                      \
        _Pragma("unroll")                                                   \
        for (int mf = 0; mf < 4; ++mf)                                      \
            _Pragma("unroll")                                               \
            for (int nf = 0; nf < 4; ++nf)                                  \
                acc[mf][nf] = __builtin_amdgcn_mfma_f32_16x16x32_bf16(      \
                    af_[mf],                                                \
                    *(short8*)&bR[(((c_) * 8 + (j_)) % 3)][nf],             \
                    acc[mf][nf], 0, 0, 0);                                  \
        __builtin_amdgcn_s_setprio(0);                                      \
        } while (0)

#define CHUNK_STD(c_) do {                                                  \
        A_ROUND(0, (c_)+1); A_ROUND(1, (c_)+1); A_ROUND(2, (c_)+1);         \
        A_ROUND(3, (c_)+1); A_ROUND(4, (c_)+1);                             \
        B_ISSUE((c_)*8+2, (((c_)*8+2)%3)); VMW(13); MFMA_TAP(c_, 0);        \
        B_ISSUE((c_)*8+3, (((c_)*8+3)%3)); VMW(13); MFMA_TAP(c_, 1);        \
        B_ISSUE((c_)*8+4, (((c_)*8+4)%3)); VMW(8);  MFMA_TAP(c_, 2);        \
        BAR();                                                              \
        B_ISSUE((c_)*8+5, (((c_)*8+5)%3)); VMW(8);  MFMA_TAP(c_, 3);        \
        B_ISSUE((c_)*8+6, (((c_)*8+6)%3)); VMW(8);  MFMA_TAP(c_, 4);        \
        B_ISSUE((c_)*8+7, (((c_)*8+7)%3)); VMW(8);  MFMA_TAP(c_, 5);        \
        CVT_ROUND(0, ((c_)+1)&1);                                           \
        B_ISSUE((c_)*8+8, (((c_)*8+8)%3)); VMW(8);  MFMA_TAP(c_, 6);        \
        CVT_ROUND(1, ((c_)+1)&1);                                           \
        B_ISSUE((c_)*8+9, (((c_)*8+9)%3)); VMW(8);  MFMA_TAP(c_, 7);        \
        CVT_ROUND(2, ((c_)+1)&1);                                           \
        LKW(); BAR();                                                       \
        } while (0)

    float bf4[4];
    #pragma unroll
    for (int nf = 0; nf < 4; ++nf)
        bf4[nf] = bias[fh * 128 + wf2 * 64 + nf * 16 + l16];

    floatx4 acc[4][4];
    #pragma unroll
    for (int mf = 0; mf < 4; ++mf)
        #pragma unroll
        for (int nf = 0; nf < 4; ++nf)
            acc[mf][nf] = (floatx4){0.f, 0.f, 0.f, 0.f};

    intx4 bR[3][4];

    // ---- prologue: stage+convert chunk 0, prime B(0),B(1) ----
    A_ROUND(0, 0); A_ROUND(1, 0); A_ROUND(2, 0); A_ROUND(3, 0); A_ROUND(4, 0);
    B_ISSUE(0, 0); B_ISSUE(1, 1);
    VMW(8);                        // A(0) retired; B(0),B(1) stay in flight
    BAR();
    CVT_ROUND(0, 0); CVT_ROUND(1, 0); CVT_ROUND(2, 0);
    LKW(); BAR();

    CHUNK_STD(0); CHUNK_STD(1); CHUNK_STD(2); CHUNK_STD(3);
    CHUNK_STD(4); CHUNK_STD(5); CHUNK_STD(6);

    // ---- last chunk (c=7): no A staging, no CVT ----
    B_ISSUE(58, (58 % 3)); VMW(8); MFMA_TAP(7, 0);
    B_ISSUE(59, (59 % 3)); VMW(8); MFMA_TAP(7, 1);
    B_ISSUE(60, (60 % 3)); VMW(8); MFMA_TAP(7, 2);
    B_ISSUE(61, (61 % 3)); VMW(8); MFMA_TAP(7, 3);
    B_ISSUE(62, (62 % 3)); VMW(8); MFMA_TAP(7, 4);
    B_ISSUE(63, (63 % 3)); VMW(8); MFMA_TAP(7, 5);
    VMW(4); MFMA_TAP(7, 6);
    VMW(0); MFMA_TAP(7, 7);

    // ---- epilogue: + cnt(t)*256*bias; C/D map col=l16 (f), row=q*4+r ----
    #pragma unroll
    for (int mf = 0; mf < 4; ++mf) {
        #pragma unroll
        for (int nf = 0; nf < 4; ++nf) {
            const int f = fh * 128 + wf2 * 64 + nf * 16 + l16;
            #pragma unroll
            for (int r = 0; r < 4; ++r) {
                const int t = t0 + wm * 64 + mf * 16 + q * 4 + r;
                const int jmin = (t < T_ - SH) ? 0 : (((t - (T_ - SH)) >> 2) + 1);
                out[(size_t)(b * T_ + t) * F_ + f] =
                    acc[mf][nf][r] + (float)(8 - jmin) * 256.0f * bf4[nf];
            }
        }
    }
#undef VMW
#undef LKW
#undef BAR
#undef A_ROUND
#undef B_ISSUE
#undef CVT_ROUND
#undef MFMA_TAP
#undef CHUNK_STD
}

extern "C" void kernel_launch(void* const* d_in, const int* in_sizes, int n_in,
                              void* d_out, int out_size, void* d_ws, size_t ws_size,
                              hipStream_t stream) {
    const float* x    = (const float*)d_in[0];
    const float* W    = (const float*)d_in[1];   // (C,KT,F)
    const float* bias = (const float*)d_in[2];
    float* out = (float*)d_out;
    ushort* Wf = (ushort*)d_ws;                  // 1 MiB scratch

    wprep_kernel<<<256, 256, 0, stream>>>(W, Wf);
    deconv_kernel<<<512, 256, 0, stream>>>(x, Wf, bias, out);
}